// Round 5
// baseline (207.739 us; speedup 1.0000x reference)
//
#include <hip/hip_runtime.h>

typedef _Float16 f16;
typedef f16 f16x2 __attribute__((ext_vector_type(2)));
typedef f16 f16x4 __attribute__((ext_vector_type(4)));
typedef f16 f16x8 __attribute__((ext_vector_type(8)));
typedef float f32x4 __attribute__((ext_vector_type(4)));

#define MFMA32(A, B, C) __builtin_amdgcn_mfma_f32_16x16x32_f16(A, B, C, 0, 0, 0)
#define MFMA16(A, B, C) __builtin_amdgcn_mfma_f32_16x16x16f16(A, B, C, 0, 0, 0)

// scores = q.k / sqrt(64), folded with log2(e) into q so softmax uses exp2.
#define QSCALE (0.125f * 1.44269504088896340736f)

// v_cvt_pkrtz returns __fp16x2; bit-cast to our _Float16-based f16x2.
__device__ __forceinline__ f16x2 pkrtz(float a, float b) {
  return __builtin_bit_cast(f16x2, __builtin_amdgcn_cvt_pkrtz(a, b));
}

// ---------------------------------------------------------------------------
// Kernel 0: transpose + cast W: Wt[n=192][k=768] f16 from W[768][64] fp32.
// ---------------------------------------------------------------------------
__global__ __launch_bounds__(256) void wtrans_kernel(
    const float* __restrict__ Wq, const float* __restrict__ Wk,
    const float* __restrict__ Wv, f16* __restrict__ Wt) {
  int gid = blockIdx.x * 256 + threadIdx.x;
  if (gid >= 3 * 64 * 768) return;
  int wsel = gid / (64 * 768);
  int rem = gid - wsel * (64 * 768);
  int nloc = rem / 768;
  int kk = rem - nloc * 768;
  const float* W = (wsel == 0) ? Wq : ((wsel == 1) ? Wk : Wv);
  Wt[gid] = (f16)W[kk * 64 + nloc];
}

// ---------------------------------------------------------------------------
// Kernel 1: projection GEMM — LDS-FREE, BARRIER-FREE. Each wave loads its
// MFMA A/B fragments directly global->VGPR (16 rows x 64 B per frag-load,
// coalesced; W is L2-resident). 32-row m-tiles, grid 512 = 2 blocks/CU =
// 8 waves/CU. Wave w: rows (w>>1)*16..+15, N-half (w&1)*96..+95 (6 MFMA/it).
// x cast fp32->f16 in-register via v_cvt_pkrtz.
// ---------------------------------------------------------------------------
__global__ __launch_bounds__(256) void proj_kernel(
    const float* __restrict__ x, const f16* __restrict__ Wt,
    const float* __restrict__ bq, const float* __restrict__ bk,
    const float* __restrict__ bv, f16* __restrict__ qo, f16* __restrict__ ko,
    f16* __restrict__ vt) {
  const int t = threadIdx.x;
  const int w = t >> 6;
  const int lane = t & 63;
  const int ln = lane & 15;
  const int quad = lane >> 4;
  const int h = w & 1;    // N-half: cols h*96 .. h*96+95
  const int mg = w >> 1;  // row group: rows mg*16 .. +15
  const int r0 = blockIdx.x * 32;
  const int row = r0 + mg * 16 + ln;

  f32x4 acc[6];
#pragma unroll
  for (int i = 0; i < 6; i++) acc[i] = (f32x4){0.f, 0.f, 0.f, 0.f};

  const float* xr = x + row * 768 + quad * 8;
  const f16* wb = Wt + (h * 96 + ln) * 768 + quad * 8;

#pragma unroll 4
  for (int kc = 0; kc < 24; kc++) {
    const float* xp = xr + kc * 32;
    float4 xa = *(const float4*)xp;
    float4 xb = *(const float4*)(xp + 4);
    union { f16x2 h2[4]; f16x8 h8; } u;
    u.h2[0] = pkrtz(xa.x, xa.y);
    u.h2[1] = pkrtz(xa.z, xa.w);
    u.h2[2] = pkrtz(xb.x, xb.y);
    u.h2[3] = pkrtz(xb.z, xb.w);
    f16x8 af = u.h8;
#pragma unroll
    for (int nt = 0; nt < 6; nt++) {
      f16x8 bf = *(const f16x8*)(wb + nt * (16 * 768) + kc * 32);
      acc[nt] = MFMA32(af, bf, acc[nt]);
    }
  }

  // epilogue: C layout col(n-in-tile)=ln, row(m-in-tile)=quad*4+r
  const int rowg = r0 + mg * 16 + quad * 4;
  if (h == 0) {
    // nt 0..3 -> q (d = nt*16+ln), pre-scaled; nt 4,5 -> k (d-64)
#pragma unroll
    for (int nt = 0; nt < 4; nt++) {
      int d = nt * 16 + ln;
      float bb = bq[d];
#pragma unroll
      for (int r = 0; r < 4; r++)
        qo[(rowg + r) * 64 + d] = (f16)((acc[nt][r] + bb) * QSCALE);
    }
#pragma unroll
    for (int nt = 4; nt < 6; nt++) {
      int d = nt * 16 + ln - 64;  // 0..47
      float bb = bk[d];
#pragma unroll
      for (int r = 0; r < 4; r++)
        ko[(rowg + r) * 64 + d] = (f16)(acc[nt][r] + bb);
    }
  } else {
    // nt 0,1 -> k (d = 32+nt*16+ln); nt 2..5 -> v (dv = nt*16+ln-32)
#pragma unroll
    for (int nt = 0; nt < 2; nt++) {
      int d = 32 + nt * 16 + ln;
      float bb = bk[d];
#pragma unroll
      for (int r = 0; r < 4; r++)
        ko[(rowg + r) * 64 + d] = (f16)(acc[nt][r] + bb);
    }
    const int bidx = r0 >> 12;
    const int sb = rowg & 4095;
#pragma unroll
    for (int nt = 2; nt < 6; nt++) {
      int dv = nt * 16 + ln - 32;  // 0..63
      float bb = bv[dv];
      f16x4 hv;
#pragma unroll
      for (int r = 0; r < 4; r++) hv[r] = (f16)(acc[nt][r] + bb);
      *(f16x4*)&vt[((bidx * 64 + dv) << 12) + sb] = hv;
    }
  }
}

// ---------------------------------------------------------------------------
// Kernel 2: flash attention, KV-SPLIT x CS. Grid (64 qt, 4 b, CS chunks).
// CS=8 -> 2048 blocks = 8 blocks/CU (LDS cap) = 32 waves/CU.
// Transposed scores St = K.Q^T: P lands directly in 16x16x16 A-layout.
// Partials stored f16 (unnormalized o) + fp32 (m, l).
// ---------------------------------------------------------------------------
template <int CS>
__global__ __launch_bounds__(256, 8) void attn_kernel(
    const f16* __restrict__ qo, const f16* __restrict__ ko,
    const f16* __restrict__ vt, f16* __restrict__ po,
    float* __restrict__ pm, float* __restrict__ pl) {
  constexpr int NK = 4096 / CS;
  __shared__ f16 Ksh[64][72];  // [key][d]
  __shared__ f16 Vsh[64][72];  // [d][key]

  const int t = threadIdx.x;
  const int w = t >> 6;
  const int lane = t & 63;
  const int ln = lane & 15;
  const int quad = lane >> 4;
  const int qt = blockIdx.x;
  const int b = blockIdx.y;
  const int c = blockIdx.z;

  const int qoff = (b * 4096 + qt * 64 + w * 16 + ln) * 64 + quad * 8;
  const f16x8 bq0 = *(const f16x8*)(qo + qoff);
  const f16x8 bq1 = *(const f16x8*)(qo + qoff + 32);

  f32x4 o[4];
#pragma unroll
  for (int i = 0; i < 4; i++) o[i] = (f32x4){0.f, 0.f, 0.f, 0.f};
  float m_s = -__builtin_inff();
  float l_s = 0.f;

  const int rr = t >> 3;       // 0..31
  const int cc = (t & 7) * 8;  // 0..56
  const f16* kbase = ko + (b * 4096 + c * NK) * 64;
  const f16* vbase = vt + b * 64 * 4096 + c * NK;

  for (int kt = 0; kt < NK / 64; kt++) {
    __syncthreads();
    const int ks0 = kt * 64;
    *(f16x8*)&Ksh[rr][cc]      = *(const f16x8*)(kbase + (ks0 + rr) * 64 + cc);
    *(f16x8*)&Ksh[rr + 32][cc] = *(const f16x8*)(kbase + (ks0 + rr + 32) * 64 + cc);
    *(f16x8*)&Vsh[rr][cc]      = *(const f16x8*)(vbase + rr * 4096 + ks0 + cc);
    *(f16x8*)&Vsh[rr + 32][cc] = *(const f16x8*)(vbase + (rr + 32) * 4096 + ks0 + cc);
    __syncthreads();

    f32x4 st[4];
#pragma unroll
    for (int i = 0; i < 4; i++) st[i] = (f32x4){0.f, 0.f, 0.f, 0.f};
#pragma unroll
    for (int nt = 0; nt < 4; nt++) {
      f16x8 a0 = *(const f16x8*)&Ksh[nt * 16 + ln][quad * 8];
      f16x8 a1 = *(const f16x8*)&Ksh[nt * 16 + ln][32 + quad * 8];
      st[nt] = MFMA32(a0, bq0, st[nt]);
      st[nt] = MFMA32(a1, bq1, st[nt]);
    }

    float vmax = st[0][0];
#pragma unroll
    for (int nt = 0; nt < 4; nt++)
#pragma unroll
      for (int r = 0; r < 4; r++) vmax = fmaxf(vmax, st[nt][r]);
    vmax = fmaxf(vmax, __shfl_xor(vmax, 16));
    vmax = fmaxf(vmax, __shfl_xor(vmax, 32));
    const float mn = fmaxf(m_s, vmax);
    const float al = exp2f(m_s - mn);
    m_s = mn;

    float pv[4][4];
    float rs = 0.f;
#pragma unroll
    for (int nt = 0; nt < 4; nt++)
#pragma unroll
      for (int r = 0; r < 4; r++) {
        pv[nt][r] = exp2f(st[nt][r] - mn);
        rs += pv[nt][r];
      }
    rs += __shfl_xor(rs, 16);
    rs += __shfl_xor(rs, 32);
    l_s = l_s * al + rs;

    float alr[4];
#pragma unroll
    for (int r = 0; r < 4; r++) alr[r] = __shfl(al, quad * 4 + r);
#pragma unroll
    for (int dt = 0; dt < 4; dt++)
#pragma unroll
      for (int r = 0; r < 4; r++) o[dt][r] *= alr[r];

    // P already in 16x16x16 A-layout; pack pairs via v_cvt_pkrtz
    f16x4 pa[4];
#pragma unroll
    for (int nt = 0; nt < 4; nt++) {
      union { f16x2 h2[2]; f16x4 h4; } u;
      u.h2[0] = pkrtz(pv[nt][0], pv[nt][1]);
      u.h2[1] = pkrtz(pv[nt][2], pv[nt][3]);
      pa[nt] = u.h4;
    }

#pragma unroll
    for (int nt = 0; nt < 4; nt++)
#pragma unroll
      for (int dt = 0; dt < 4; dt++) {
        f16x4 bv = *(const f16x4*)&Vsh[dt * 16 + ln][nt * 16 + quad * 4];
        o[dt] = MFMA16(pa[nt], bv, o[dt]);
      }
  }

  const int blin = (b * CS + c) * 64 + qt;
  f16* pob = po + blin * 4096;
#pragma unroll
  for (int dt = 0; dt < 4; dt++)
#pragma unroll
    for (int r = 0; r < 4; r++)
      pob[(w * 16 + quad * 4 + r) * 64 + dt * 16 + ln] = (f16)o[dt][r];
  if (quad == 0) {
    pm[blin * 64 + w * 16 + ln] = m_s;
    pl[blin * 64 + w * 16 + ln] = l_s;
  }
}

// ---------------------------------------------------------------------------
// Kernel 3: merge the CS KV-chunks.
// ---------------------------------------------------------------------------
template <int CS>
__global__ __launch_bounds__(256) void merge_kernel(
    const f16* __restrict__ po, const float* __restrict__ pm,
    const float* __restrict__ pl, float* __restrict__ out) {
  const int qt = blockIdx.x;
  const int b = blockIdx.y;
  const int z = blockIdx.z;
  const int d = threadIdx.x & 63;
  const int qw = threadIdx.x >> 6;

#pragma unroll
  for (int q0 = 0; q0 < 4; q0++) {
    const int q = z * 16 + q0 * 4 + qw;
    float mm[CS], ll[CS];
#pragma unroll
    for (int c = 0; c < CS; c++) {
      const int blin = (b * CS + c) * 64 + qt;
      mm[c] = pm[blin * 64 + q];
      ll[c] = pl[blin * 64 + q];
    }
    float ms = mm[0];
#pragma unroll
    for (int c = 1; c < CS; c++) ms = fmaxf(ms, mm[c]);
    float den = 0.f, num = 0.f;
#pragma unroll
    for (int c = 0; c < CS; c++) {
      const int blin = (b * CS + c) * 64 + qt;
      const float a = exp2f(mm[c] - ms);
      den += a * ll[c];
      num += a * (float)po[blin * 4096 + q * 64 + d];
    }
    out[(b * 4096 + qt * 64 + q) * 64 + d] = num / den;
  }
}

// ---------------------------------------------------------------------------
extern "C" void kernel_launch(void* const* d_in, const int* in_sizes, int n_in,
                              void* d_out, int out_size, void* d_ws,
                              size_t ws_size, hipStream_t stream) {
  const float* x = (const float*)d_in[0];
  const float* Wq = (const float*)d_in[1];
  const float* bq = (const float*)d_in[2];
  const float* Wk = (const float*)d_in[3];
  const float* bk = (const float*)d_in[4];
  const float* Wv = (const float*)d_in[5];
  const float* bv = (const float*)d_in[6];
  float* out = (float*)d_out;

  char* ws = (char*)d_ws;
  f16* Wt = (f16*)ws;                           // 294912 B
  f16* qo = (f16*)(ws + 294912);                // 2 MiB
  f16* ko = (f16*)(ws + 294912 + 2097152);      // 2 MiB
  f16* vt = (f16*)(ws + 294912 + 2 * 2097152);  // 2 MiB
  const size_t base = 6586368;

  wtrans_kernel<<<dim3(576), dim3(256), 0, stream>>>(Wq, Wk, Wv, Wt);
  proj_kernel<<<dim3(512), dim3(256), 0, stream>>>(x, Wt, bq, bk, bv, qo, ko, vt);

  const size_t need8 = base + (size_t)2048 * 4096 * 2 + 2 * 524288;  // 24.4 MB
  if (ws_size >= need8) {
    f16* po = (f16*)(ws + base);
    float* pm = (float*)(ws + base + (size_t)2048 * 4096 * 2);
    float* pl = (float*)(ws + base + (size_t)2048 * 4096 * 2 + 524288);
    attn_kernel<8><<<dim3(64, 4, 8), dim3(256), 0, stream>>>(qo, ko, vt, po, pm, pl);
    merge_kernel<8><<<dim3(64, 4, 4), dim3(256), 0, stream>>>(po, pm, pl, out);
  } else {
    f16* po = (f16*)(ws + base);
    float* pm = (float*)(ws + base + (size_t)1024 * 4096 * 2);
    float* pl = (float*)(ws + base + (size_t)1024 * 4096 * 2 + 262144);
    attn_kernel<4><<<dim3(64, 4, 4), dim3(256), 0, stream>>>(qo, ko, vt, po, pm, pl);
    merge_kernel<4><<<dim3(64, 4, 4), dim3(256), 0, stream>>>(po, pm, pl, out);
  }
}

// Round 6
// 174.282 us; speedup vs baseline: 1.1920x; 1.1920x over previous
//
#include <hip/hip_runtime.h>

typedef _Float16 f16;
typedef f16 f16x2 __attribute__((ext_vector_type(2)));
typedef f16 f16x4 __attribute__((ext_vector_type(4)));
typedef f16 f16x8 __attribute__((ext_vector_type(8)));
typedef float f32x4 __attribute__((ext_vector_type(4)));

#define MFMA32(A, B, C) __builtin_amdgcn_mfma_f32_16x16x32_f16(A, B, C, 0, 0, 0)
#define MFMA16(A, B, C) __builtin_amdgcn_mfma_f32_16x16x16f16(A, B, C, 0, 0, 0)

// scores = q.k / sqrt(64), folded with log2(e) into q so softmax uses exp2.
#define QSCALE (0.125f * 1.44269504088896340736f)

__device__ __forceinline__ f16x2 pkrtz(float a, float b) {
  return __builtin_bit_cast(f16x2, __builtin_amdgcn_cvt_pkrtz(a, b));
}

// ---------------------------------------------------------------------------
// Kernel 0: W transpose via LDS (coalesced read AND write).
// Wt[n=192][k=768] f16 from W[768][64] fp32. Grid (12 k-tiles, 3 matrices).
// ---------------------------------------------------------------------------
__global__ __launch_bounds__(256) void wtrans_kernel(
    const float* __restrict__ Wq, const float* __restrict__ Wk,
    const float* __restrict__ Wv, f16* __restrict__ Wt) {
  __shared__ float T[64][65];
  const int t = threadIdx.x;
  const int kt = blockIdx.x;  // k-tile (64 rows of W)
  const int z = blockIdx.y;   // 0=q 1=k 2=v
  const float* W = (z == 0) ? Wq : ((z == 1) ? Wk : Wv);

  {  // coalesced load: thread covers row kl, cols c0..c0+15
    const int kl = t >> 2, c0 = (t & 3) * 16;
    const float* wp = W + (kt * 64 + kl) * 64 + c0;
    float4 v0 = *(const float4*)wp;
    float4 v1 = *(const float4*)(wp + 4);
    float4 v2 = *(const float4*)(wp + 8);
    float4 v3 = *(const float4*)(wp + 12);
    float* Tr = &T[kl][c0];
    Tr[0] = v0.x; Tr[1] = v0.y; Tr[2] = v0.z; Tr[3] = v0.w;
    Tr[4] = v1.x; Tr[5] = v1.y; Tr[6] = v1.z; Tr[7] = v1.w;
    Tr[8] = v2.x; Tr[9] = v2.y; Tr[10] = v2.z; Tr[11] = v2.w;
    Tr[12] = v3.x; Tr[13] = v3.y; Tr[14] = v3.z; Tr[15] = v3.w;
  }
  __syncthreads();
  {  // coalesced store: thread covers Wt row n, k-range k0..k0+15
    const int n = t >> 2, k0 = (t & 3) * 16;
    union { f16x2 h2[8]; f16x8 h8[2]; } u;
#pragma unroll
    for (int i = 0; i < 8; i++)
      u.h2[i] = pkrtz(T[k0 + 2 * i][n], T[k0 + 2 * i + 1][n]);
    f16* dst = Wt + (z * 64 + n) * 768 + kt * 64 + k0;
    *(f16x8*)dst = u.h8[0];
    *(f16x8*)(dst + 8) = u.h8[1];
  }
}

// ---------------------------------------------------------------------------
// Kernel 1: projection GEMM. Grid (256 m-tiles, 3 splits), BK=64, LDS-staged
// with REGISTER PREFETCH of the next K-slab issued before the compute phase
// (overlaps HBM latency with MFMA). LDS 18.4 KB -> up to 8 blocks/CU.
// ---------------------------------------------------------------------------
__global__ __launch_bounds__(256, 4) void proj_kernel(
    const float* __restrict__ x, const f16* __restrict__ Wt,
    const float* __restrict__ bq, const float* __restrict__ bk,
    const float* __restrict__ bv, f16* __restrict__ qo, f16* __restrict__ ko,
    f16* __restrict__ vt) {
  __shared__ f16 Xs[64][72];
  __shared__ f16 Ws[64][72];

  const int t = threadIdx.x;
  const int w = t >> 6;
  const int lane = t & 63;
  const int ln = lane & 15;
  const int quad = lane >> 4;
  const int r0 = blockIdx.x * 64;
  const int y = blockIdx.y;  // 0=q 1=k 2=v

  f32x4 acc[4];
#pragma unroll
  for (int i = 0; i < 4; i++) acc[i] = (f32x4){0.f, 0.f, 0.f, 0.f};

  // staging: thread covers row srow, 16 cols at scol (x: floats; W: halves)
  const int srow = t >> 2;
  const int scol = (t & 3) * 16;
  const float* xr = x + (r0 + srow) * 768 + scol;
  const f16* wr = Wt + (y * 64 + srow) * 768 + scol;

  float4 xa0, xa1, xa2, xa3;
  f16x8 wf0, wf1;
  // preload slab 0
  xa0 = *(const float4*)xr; xa1 = *(const float4*)(xr + 4);
  xa2 = *(const float4*)(xr + 8); xa3 = *(const float4*)(xr + 12);
  wf0 = *(const f16x8*)wr; wf1 = *(const f16x8*)(wr + 8);

  for (int kc = 0; kc < 12; kc++) {
    __syncthreads();  // LDS free to overwrite
    {
      union { f16x2 h2[4]; f16x8 h8; } u0, u1;
      u0.h2[0] = pkrtz(xa0.x, xa0.y); u0.h2[1] = pkrtz(xa0.z, xa0.w);
      u0.h2[2] = pkrtz(xa1.x, xa1.y); u0.h2[3] = pkrtz(xa1.z, xa1.w);
      u1.h2[0] = pkrtz(xa2.x, xa2.y); u1.h2[1] = pkrtz(xa2.z, xa2.w);
      u1.h2[2] = pkrtz(xa3.x, xa3.y); u1.h2[3] = pkrtz(xa3.z, xa3.w);
      *(f16x8*)&Xs[srow][scol] = u0.h8;
      *(f16x8*)&Xs[srow][scol + 8] = u1.h8;
      *(f16x8*)&Ws[srow][scol] = wf0;
      *(f16x8*)&Ws[srow][scol + 8] = wf1;
    }
    if (kc + 1 < 12) {  // prefetch next slab into regs; overlaps compute below
      const float* xp = xr + (kc + 1) * 64;
      xa0 = *(const float4*)xp; xa1 = *(const float4*)(xp + 4);
      xa2 = *(const float4*)(xp + 8); xa3 = *(const float4*)(xp + 12);
      const f16* wp = wr + (kc + 1) * 64;
      wf0 = *(const f16x8*)wp; wf1 = *(const f16x8*)(wp + 8);
    }
    __syncthreads();  // LDS ready

    f16x8 a0 = *(const f16x8*)&Xs[w * 16 + ln][quad * 8];
    f16x8 a1 = *(const f16x8*)&Xs[w * 16 + ln][32 + quad * 8];
#pragma unroll
    for (int nt = 0; nt < 4; nt++) {
      f16x8 b0 = *(const f16x8*)&Ws[nt * 16 + ln][quad * 8];
      f16x8 b1 = *(const f16x8*)&Ws[nt * 16 + ln][32 + quad * 8];
      acc[nt] = MFMA32(a0, b0, acc[nt]);
      acc[nt] = MFMA32(a1, b1, acc[nt]);
    }
  }

  // epilogue: C layout col=ln (+16nt) = n, row=quad*4+r (+16w) = m
  const int rowg = r0 + w * 16 + quad * 4;
  if (y == 0) {  // q, pre-scaled
#pragma unroll
    for (int nt = 0; nt < 4; nt++) {
      int d = nt * 16 + ln;
      float bb = bq[d];
#pragma unroll
      for (int r = 0; r < 4; r++)
        qo[(rowg + r) * 64 + d] = (f16)((acc[nt][r] + bb) * QSCALE);
    }
  } else if (y == 1) {  // k
#pragma unroll
    for (int nt = 0; nt < 4; nt++) {
      int d = nt * 16 + ln;
      float bb = bk[d];
#pragma unroll
      for (int r = 0; r < 4; r++)
        ko[(rowg + r) * 64 + d] = (f16)(acc[nt][r] + bb);
    }
  } else {  // v, transposed store vt[b][d][s]
    const int bidx = r0 >> 12;
    const int sb = rowg & 4095;
#pragma unroll
    for (int nt = 0; nt < 4; nt++) {
      int dv = nt * 16 + ln;
      float bb = bv[dv];
      f16x4 hv;
#pragma unroll
      for (int r = 0; r < 4; r++) hv[r] = (f16)(acc[nt][r] + bb);
      *(f16x4*)&vt[((bidx * 64 + dv) << 12) + sb] = hv;
    }
  }
}

// ---------------------------------------------------------------------------
// Kernel 2: flash attention, KV-SPLIT x CS, XCD-PINNED swizzle: 1-D grid,
// c = bid % CS so round-robin dispatch keeps one KV chunk per XCD (per-XCD
// working set = chunk (512 KB) + qo (2 MB) < 4 MiB L2). po stored
// lane-contiguous (32 B/lane) for fully coalesced writes.
// ---------------------------------------------------------------------------
template <int CS>
__global__ __launch_bounds__(256, 8) void attn_kernel(
    const f16* __restrict__ qo, const f16* __restrict__ ko,
    const f16* __restrict__ vt, f16* __restrict__ po,
    float* __restrict__ pm, float* __restrict__ pl) {
  constexpr int NK = 4096 / CS;
  __shared__ f16 Ksh[64][72];  // [key][d]
  __shared__ f16 Vsh[64][72];  // [d][key]

  const int t = threadIdx.x;
  const int w = t >> 6;
  const int lane = t & 63;
  const int ln = lane & 15;
  const int quad = lane >> 4;
  const int bid = blockIdx.x;
  const int c = bid % CS;          // chunk pinned per XCD (bid%8 round-robin)
  const int b = (bid / CS) & 3;
  const int qt = bid / (CS * 4);

  const int qoff = (b * 4096 + qt * 64 + w * 16 + ln) * 64 + quad * 8;
  const f16x8 bq0 = *(const f16x8*)(qo + qoff);
  const f16x8 bq1 = *(const f16x8*)(qo + qoff + 32);

  f32x4 o[4];
#pragma unroll
  for (int i = 0; i < 4; i++) o[i] = (f32x4){0.f, 0.f, 0.f, 0.f};
  float m_s = -__builtin_inff();
  float l_s = 0.f;

  const int rr = t >> 3;       // 0..31
  const int cc = (t & 7) * 8;  // 0..56
  const f16* kbase = ko + (b * 4096 + c * NK) * 64;
  const f16* vbase = vt + b * 64 * 4096 + c * NK;

  for (int kt = 0; kt < NK / 64; kt++) {
    __syncthreads();
    const int ks0 = kt * 64;
    *(f16x8*)&Ksh[rr][cc]      = *(const f16x8*)(kbase + (ks0 + rr) * 64 + cc);
    *(f16x8*)&Ksh[rr + 32][cc] = *(const f16x8*)(kbase + (ks0 + rr + 32) * 64 + cc);
    *(f16x8*)&Vsh[rr][cc]      = *(const f16x8*)(vbase + rr * 4096 + ks0 + cc);
    *(f16x8*)&Vsh[rr + 32][cc] = *(const f16x8*)(vbase + (rr + 32) * 4096 + ks0 + cc);
    __syncthreads();

    f32x4 st[4];
#pragma unroll
    for (int i = 0; i < 4; i++) st[i] = (f32x4){0.f, 0.f, 0.f, 0.f};
#pragma unroll
    for (int nt = 0; nt < 4; nt++) {
      f16x8 a0 = *(const f16x8*)&Ksh[nt * 16 + ln][quad * 8];
      f16x8 a1 = *(const f16x8*)&Ksh[nt * 16 + ln][32 + quad * 8];
      st[nt] = MFMA32(a0, bq0, st[nt]);
      st[nt] = MFMA32(a1, bq1, st[nt]);
    }

    float vmax = st[0][0];
#pragma unroll
    for (int nt = 0; nt < 4; nt++)
#pragma unroll
      for (int r = 0; r < 4; r++) vmax = fmaxf(vmax, st[nt][r]);
    vmax = fmaxf(vmax, __shfl_xor(vmax, 16));
    vmax = fmaxf(vmax, __shfl_xor(vmax, 32));
    const float mn = fmaxf(m_s, vmax);
    const float al = exp2f(m_s - mn);
    m_s = mn;

    float pv[4][4];
    float rs = 0.f;
#pragma unroll
    for (int nt = 0; nt < 4; nt++)
#pragma unroll
      for (int r = 0; r < 4; r++) {
        pv[nt][r] = exp2f(st[nt][r] - mn);
        rs += pv[nt][r];
      }
    rs += __shfl_xor(rs, 16);
    rs += __shfl_xor(rs, 32);
    l_s = l_s * al + rs;

    float alr[4];
#pragma unroll
    for (int r = 0; r < 4; r++) alr[r] = __shfl(al, quad * 4 + r);
#pragma unroll
    for (int dt = 0; dt < 4; dt++)
#pragma unroll
      for (int r = 0; r < 4; r++) o[dt][r] *= alr[r];

    f16x4 pa[4];
#pragma unroll
    for (int nt = 0; nt < 4; nt++) {
      union { f16x2 h2[2]; f16x4 h4; } u;
      u.h2[0] = pkrtz(pv[nt][0], pv[nt][1]);
      u.h2[1] = pkrtz(pv[nt][2], pv[nt][3]);
      pa[nt] = u.h4;
    }

#pragma unroll
    for (int nt = 0; nt < 4; nt++)
#pragma unroll
      for (int dt = 0; dt < 4; dt++) {
        f16x4 bv = *(const f16x4*)&Vsh[dt * 16 + ln][nt * 16 + quad * 4];
        o[dt] = MFMA16(pa[nt], bv, o[dt]);
      }
  }

  // epilogue: lane-contiguous po (32 B/lane, fully coalesced)
  const int blin = (b * CS + c) * 64 + qt;
  {
    union { f16x2 h2[8]; f16x8 h8[2]; } u;
#pragma unroll
    for (int dt = 0; dt < 4; dt++) {
      u.h2[dt * 2] = pkrtz(o[dt][0], o[dt][1]);
      u.h2[dt * 2 + 1] = pkrtz(o[dt][2], o[dt][3]);
    }
    f16* p = po + (((size_t)blin * 4 + w) * 64 + lane) * 16;
    *(f16x8*)p = u.h8[0];
    *(f16x8*)(p + 8) = u.h8[1];
  }
  if (quad == 0) {
    pm[blin * 64 + w * 16 + ln] = m_s;
    pl[blin * 64 + w * 16 + ln] = l_s;
  }
}

// ---------------------------------------------------------------------------
// Kernel 3: merge CS chunks. Thread (w,lane) reads back exactly the po
// elements it (i.e. its attn counterpart) wrote -> coalesced 32 B/lane.
// ---------------------------------------------------------------------------
template <int CS>
__global__ __launch_bounds__(256) void merge_kernel(
    const f16* __restrict__ po, const float* __restrict__ pm,
    const float* __restrict__ pl, float* __restrict__ out) {
  const int qt = blockIdx.x;
  const int b = blockIdx.y;
  const int t = threadIdx.x;
  const int w = t >> 6;
  const int lane = t & 63;
  const int ln = lane & 15;
  const int quad = lane >> 4;

  float mm[CS][4], ll[CS][4];
#pragma unroll
  for (int c = 0; c < CS; c++) {
    const int blin = (b * CS + c) * 64 + qt;
#pragma unroll
    for (int r = 0; r < 4; r++) {
      mm[c][r] = pm[blin * 64 + w * 16 + quad * 4 + r];
      ll[c][r] = pl[blin * 64 + w * 16 + quad * 4 + r];
    }
  }
  float ms[4];
#pragma unroll
  for (int r = 0; r < 4; r++) {
    ms[r] = mm[0][r];
#pragma unroll
    for (int c = 1; c < CS; c++) ms[r] = fmaxf(ms[r], mm[c][r]);
  }

  f32x4 o2[4];
#pragma unroll
  for (int i = 0; i < 4; i++) o2[i] = (f32x4){0.f, 0.f, 0.f, 0.f};
  float den[4] = {0.f, 0.f, 0.f, 0.f};

#pragma unroll
  for (int c = 0; c < CS; c++) {
    const int blin = (b * CS + c) * 64 + qt;
    float a[4];
#pragma unroll
    for (int r = 0; r < 4; r++) {
      a[r] = exp2f(mm[c][r] - ms[r]);
      den[r] += a[r] * ll[c][r];
    }
    const f16* p = po + (((size_t)blin * 4 + w) * 64 + lane) * 16;
    f16x8 l0 = *(const f16x8*)p;
    f16x8 l1 = *(const f16x8*)(p + 8);
#pragma unroll
    for (int dt = 0; dt < 2; dt++)
#pragma unroll
      for (int r = 0; r < 4; r++) {
        o2[dt][r] += a[r] * (float)l0[dt * 4 + r];
        o2[dt + 2][r] += a[r] * (float)l1[dt * 4 + r];
      }
  }

  const int orow = b * 4096 + qt * 64 + w * 16 + quad * 4;
#pragma unroll
  for (int r = 0; r < 4; r++) {
    float inv = 1.0f / den[r];
#pragma unroll
    for (int dt = 0; dt < 4; dt++)
      out[(orow + r) * 64 + dt * 16 + ln] = o2[dt][r] * inv;
  }
}

// ---------------------------------------------------------------------------
extern "C" void kernel_launch(void* const* d_in, const int* in_sizes, int n_in,
                              void* d_out, int out_size, void* d_ws,
                              size_t ws_size, hipStream_t stream) {
  const float* x = (const float*)d_in[0];
  const float* Wq = (const float*)d_in[1];
  const float* bq = (const float*)d_in[2];
  const float* Wk = (const float*)d_in[3];
  const float* bk = (const float*)d_in[4];
  const float* Wv = (const float*)d_in[5];
  const float* bv = (const float*)d_in[6];
  float* out = (float*)d_out;

  char* ws = (char*)d_ws;
  f16* Wt = (f16*)ws;                           // 294912 B
  f16* qo = (f16*)(ws + 294912);                // 2 MiB
  f16* ko = (f16*)(ws + 294912 + 2097152);      // 2 MiB
  f16* vt = (f16*)(ws + 294912 + 2 * 2097152);  // 2 MiB
  const size_t base = 6586368;

  wtrans_kernel<<<dim3(12, 3), dim3(256), 0, stream>>>(Wq, Wk, Wv, Wt);
  proj_kernel<<<dim3(256, 3), dim3(256), 0, stream>>>(x, Wt, bq, bk, bv, qo, ko, vt);

  const size_t need8 = base + (size_t)2048 * 4096 * 2 + 2 * 524288;  // ~24.4 MB
  if (ws_size >= need8) {
    f16* po = (f16*)(ws + base);
    float* pm = (float*)(ws + base + (size_t)2048 * 4096 * 2);
    float* pl = (float*)(ws + base + (size_t)2048 * 4096 * 2 + 524288);
    attn_kernel<8><<<dim3(2048), dim3(256), 0, stream>>>(qo, ko, vt, po, pm, pl);
    merge_kernel<8><<<dim3(64, 4), dim3(256), 0, stream>>>(po, pm, pl, out);
  } else {
    f16* po = (f16*)(ws + base);
    float* pm = (float*)(ws + base + (size_t)1024 * 4096 * 2);
    float* pl = (float*)(ws + base + (size_t)1024 * 4096 * 2 + 262144);
    attn_kernel<4><<<dim3(1024), dim3(256), 0, stream>>>(qo, ko, vt, po, pm, pl);
    merge_kernel<4><<<dim3(64, 4), dim3(256), 0, stream>>>(po, pm, pl, out);
  }
}